// Round 9
// baseline (138.253 us; speedup 1.0000x reference)
//
#include <hip/hip_runtime.h>

// RankPool1d: window=16, stride=1, pad=8 (zeros), rank=8 (0-based 7),
// stable argsort tie-break. Outputs: values f32 [OUT_LEN], sel (as f32) [OUT_LEN].
//
// *** DIAGNOSTIC ROUND ***
// Real kernel (R6 structure, best known ~24us) + a x5-repeat clone launched
// second so it exceeds the ~40us harness fills and lands in the rocprof top-5
// with true VALUBusy/Occupancy counters. Outputs identical & deterministic
// (each rep rewrites the same values). Bench dur_us this round ~ 5-6x real.
//
// LAUNCH BOUNDS: bare (256) ONLY. Any min-waves second arg makes hipcc spill
// the w[]/R[] working set to scratch ((256,5): VGPR 48, WRITE 79MB; (256,4):
// VGPR 64, occ 1%). Do not add a second argument.

constexpr int L_IN    = 4194304;
constexpr int OUT_LEN = L_IN + 1;      // 4194305
constexpr int MOUT    = 16;            // outputs per thread
constexpr int TPB     = 256;
constexpr int OPB     = TPB * MOUT;    // 4096 outputs per block
constexpr int NBLK    = 1024;

// value LDS: element p stored at [(p&15)*256 + ((p>>4) ^ (2*(p&15)))]
__device__ __forceinline__ int lvidx(int p) {
    return (p & 15) * TPB + ((p >> 4) ^ (2 * (p & 15)));
}
// sel words: word q (outputs 4q..4q+3) at [(q&3)*256 + ((q>>2) ^ (8*(q&3)))]
__device__ __forceinline__ int lsidx(int q) {
    return (q & 3) * TPB + ((q >> 2) ^ (8 * (q & 3)));
}

__device__ __forceinline__ void rankpool_body(const float* x, float* dout,
                                              float* lv, unsigned* ws32) {
    const int t   = threadIdx.x;
    const int blk = blockIdx.x;
    const int tid = blk * TPB + t;
    const int o0  = tid * MOUT;
    const int base = o0 - 8;
    const bool extra = (tid == TPB * NBLK - 1);

    float w[32];
    if (base >= 0 && base + 32 <= L_IN) {
        const float4* p = reinterpret_cast<const float4*>(x + base);
        #pragma unroll
        for (int q = 0; q < 8; ++q) {
            float4 v = p[q];
            w[4*q+0] = v.x; w[4*q+1] = v.y; w[4*q+2] = v.z; w[4*q+3] = v.w;
        }
    } else {
        #pragma unroll
        for (int i = 0; i < 32; ++i) {
            int g = base + i;
            w[i] = (g >= 0 && g < L_IN) ? x[g] : 0.0f;
        }
    }

    int R[32];
    #pragma unroll
    for (int j = 0; j < 16; ++j) R[j] = j;
    #pragma unroll
    for (int j = 0; j < 16; ++j) {
        #pragma unroll
        for (int k = j + 1; k < 16; ++k) {
            int c = (w[k] < w[j]);
            R[j] += c;
            R[k] -= c;
        }
    }

    unsigned pk[4] = {0u, 0u, 0u, 0u};
    #pragma unroll
    for (int m = 0; m < MOUT; ++m) {
        int   sel = 0;
        float val = w[m];
        #pragma unroll
        for (int j = m; j < m + 16; ++j) {
            bool c = (R[j] == 7 + m);
            sel = c ? (j - m) : sel;
            val = c ? w[j]    : val;
        }
        lv[lvidx(t * MOUT + m)] = val;
        pk[m >> 2] |= ((unsigned)sel) << (8 * (m & 3));

        if (m < MOUT - 1) {
            const float wm = w[m];
            const float wn = w[m + 16];
            int s = 0;
            #pragma unroll
            for (int j = m + 1; j < m + 16; ++j) {
                R[j] += (int)(w[j] < wm);
                int c2 = (wn < w[j]);
                R[j] += c2;
                s    += c2;
            }
            R[m + 16] = 16 + m - s;
        }
    }
    #pragma unroll
    for (int a = 0; a < 4; ++a)
        ws32[lsidx(t * 4 + a)] = pk[a];

    if (extra) {
        const float wm = w[15], wn = w[31];
        int s = 0;
        #pragma unroll
        for (int j = 16; j < 31; ++j) {
            R[j] += (int)(w[j] < wm);
            int c2 = (wn < w[j]);
            R[j] += c2;
            s    += c2;
        }
        R[31] = 31 - s;
        int sel = 0; float val = w[16];
        #pragma unroll
        for (int j = 16; j < 32; ++j) {
            bool c = (R[j] == 23);
            sel = c ? (j - 16) : sel;
            val = c ? w[j]     : val;
        }
        dout[OUT_LEN - 1]     = val;
        dout[2 * OUT_LEN - 1] = (float)sel;
    }

    __syncthreads();

    const int blockStart = blk * OPB;
    #pragma unroll
    for (int k = 0; k < 4; ++k) {
        int p = 4 * (t + TPB * k);
        float4 v;
        v.x = lv[lvidx(p + 0)];
        v.y = lv[lvidx(p + 1)];
        v.z = lv[lvidx(p + 2)];
        v.w = lv[lvidx(p + 3)];
        *reinterpret_cast<float4*>(dout + blockStart + p) = v;
    }

    float* s0 = dout + OUT_LEN + blockStart;
    if (t < 3) {
        unsigned w0 = ws32[lsidx(0)];
        s0[t] = (float)((w0 >> (8 * t)) & 0xffu);
    }
    if (t == 3) {
        unsigned wl = ws32[lsidx(1023)];
        s0[OPB - 1] = (float)(wl >> 24);
    }
    #pragma unroll
    for (int k = 0; k < 4; ++k) {
        int q = t + TPB * k;
        if (q < 1023) {
            unsigned wa = ws32[lsidx(q)];
            unsigned wb = ws32[lsidx(q + 1)];
            float4 v;
            v.x = (float)(wa >> 24);
            v.y = (float)( wb        & 0xffu);
            v.z = (float)((wb >>  8) & 0xffu);
            v.w = (float)((wb >> 16) & 0xffu);
            *reinterpret_cast<float4*>(s0 + 3 + 4 * q) = v;
        }
    }
}

__global__ __launch_bounds__(TPB) void rankpool_kernel(const float* __restrict__ x,
                                                       float* __restrict__ dout) {
    __shared__ float    lv[MOUT * TPB];
    __shared__ unsigned ws32[4 * TPB];
    rankpool_body(x, dout, lv, ws32);
}

// Same work x5 (idempotent rewrites). Memory clobber per rep blocks DSE /
// load-hoisting so each rep is real. Lands >40us -> visible in rocprof top-5.
__global__ __launch_bounds__(TPB) void rankpool_diag(const float* __restrict__ x,
                                                     float* __restrict__ dout) {
    __shared__ float    lv[MOUT * TPB];
    __shared__ unsigned ws32[4 * TPB];
    for (int rep = 0; rep < 5; ++rep) {
        rankpool_body(x, dout, lv, ws32);
        __syncthreads();
        asm volatile("" ::: "memory");
    }
}

extern "C" void kernel_launch(void* const* d_in, const int* in_sizes, int n_in,
                              void* d_out, int out_size, void* d_ws, size_t ws_size,
                              hipStream_t stream) {
    const float* x = (const float*)d_in[0];
    float* out = (float*)d_out;
    rankpool_kernel<<<NBLK, TPB, 0, stream>>>(x, out);
    rankpool_diag<<<NBLK, TPB, 0, stream>>>(x, out);
}

// Round 10
// 25.359 us; speedup vs baseline: 5.4519x; 5.4519x over previous
//
#include <hip/hip_runtime.h>

// RankPool1d: window=16, stride=1, pad=8 (zeros), rank=8 (0-based 7),
// stable argsort tie-break. Outputs: values f32 [OUT_LEN], sel (as f32) [OUT_LEN].
//
// R10: MOUT=16, NO LDS, NO barrier (R9 diag: VGPR=148 -> 3 waves/SIMD,
// VALUBusy 51%, ~3780 VALU instr/thread; ~1200 of those were LDS-transpose
// overhead. Values store directly as aligned float4 (o0 = 16*tid); sel half
// (odd offset OUT_LEN mod 4 == 1) stored as aligned float4 via packed bytes
// + one __shfl_down: thread t covers outputs o0+3..o0+18 with own pk bytes
// 3..15 + lane+1's bytes 0..2. Lane 0 patches first 3 scalars, lane 63 ends
// at its byte15 scalar.
//
// LAUNCH BOUNDS: bare (256) ONLY. Any min-waves second arg makes hipcc spill
// the w[]/R[] working set to scratch ((256,5): VGPR 48, WRITE 79MB; (256,4):
// VGPR 64, occ 1%). Do not add a second argument.

constexpr int L_IN    = 4194304;
constexpr int OUT_LEN = L_IN + 1;      // 4194305
constexpr int MOUT    = 16;
constexpr int TPB     = 256;
constexpr int NTH     = (OUT_LEN - 1) / MOUT;   // 262144
constexpr int NBLK    = NTH / TPB;              // 1024

__global__ __launch_bounds__(TPB) void rankpool_kernel(const float* __restrict__ x,
                                                       float* __restrict__ dout) {
    const int t    = blockIdx.x * TPB + threadIdx.x;   // 0..262143
    const int lane = threadIdx.x & 63;
    const int o0   = t * MOUT;
    const int base = o0 - 8;
    const bool isLast = (t == NTH - 1);

    // ---- load 32 inputs (windows m=0..15 need base..base+30; extra +31) ----
    float w[32];
    if (base >= 0 && base + 32 <= L_IN) {
        const float4* p = reinterpret_cast<const float4*>(x + base);  // 16B aligned
        #pragma unroll
        for (int q = 0; q < 8; ++q) {
            float4 v = p[q];
            w[4*q+0] = v.x; w[4*q+1] = v.y; w[4*q+2] = v.z; w[4*q+3] = v.w;
        }
    } else {
        #pragma unroll
        for (int i = 0; i < 32; ++i) {
            int g = base + i;
            w[i] = (g >= 0 && g < L_IN) ? x[g] : 0.0f;   // PAD_VALUE = 0
        }
    }

    // ---- biased ranks for window 0 (R[j] = stable rank; init R[j]=j) ----
    int R[32];
    #pragma unroll
    for (int j = 0; j < 16; ++j) R[j] = j;
    #pragma unroll
    for (int j = 0; j < 16; ++j) {
        #pragma unroll
        for (int k = j + 1; k < 16; ++k) {
            int c = (w[k] < w[j]);
            R[j] += c;
            R[k] -= c;
        }
    }

    // ---- 16 windows: select rank==7 (biased 7+m), direct f4 stores, slide ----
    unsigned pk[4] = {0u, 0u, 0u, 0u};   // 16 sel bytes
    float va[4];                          // 4-value store ring
    #pragma unroll
    for (int m = 0; m < MOUT; ++m) {
        int   sel = 0;
        float val = w[m];
        #pragma unroll
        for (int j = m; j < m + 16; ++j) {
            bool c = (R[j] == 7 + m);
            sel = c ? (j - m) : sel;
            val = c ? w[j]    : val;
        }
        va[m & 3] = val;
        pk[m >> 2] |= ((unsigned)sel) << (8 * (m & 3));
        if ((m & 3) == 3)   // aligned: o0 + m-3 is a multiple of 4
            *reinterpret_cast<float4*>(dout + o0 + (m - 3)) =
                make_float4(va[0], va[1], va[2], va[3]);

        if (m < MOUT - 1) {
            const float wm = w[m];            // departing (oldest)
            const float wn = w[m + 16];       // entering (newest)
            int s = 0;
            #pragma unroll
            for (int j = m + 1; j < m + 16; ++j) {
                R[j] += (int)(w[j] < wm);
                int c2 = (wn < w[j]);
                R[j] += c2;
                s    += c2;
            }
            R[m + 16] = 16 + m - s;           // (15-s) + (m+1) bias
        }
    }

    // ---- sel stores: aligned float4 groups [o0+3+4g .. o0+6+4g] ----
    unsigned pn = __shfl_down(pk[0], 1, 64);  // lane+1's first 4 sel bytes
    float* s0 = dout + OUT_LEN + o0;          // (OUT_LEN+o0+3) % 4 == 0
    #pragma unroll
    for (int g = 0; g < 3; ++g) {
        unsigned a = pk[g], b = pk[g + 1];
        *reinterpret_cast<float4*>(s0 + 3 + 4 * g) =
            make_float4((float)( a >> 24),
                        (float)( b        & 0xffu),
                        (float)((b >>  8) & 0xffu),
                        (float)((b >> 16) & 0xffu));
    }
    if (lane < 63) {
        *reinterpret_cast<float4*>(s0 + 15) =
            make_float4((float)( pk[3] >> 24),
                        (float)( pn        & 0xffu),
                        (float)((pn >>  8) & 0xffu),
                        (float)((pn >> 16) & 0xffu));
    } else {
        s0[15] = (float)(pk[3] >> 24);        // own last byte only
    }
    if (lane == 0) {                          // first 3 outputs (prev thread is
        s0[0] = (float)( pk[0]        & 0xffu);   // other wave/block or none)
        s0[1] = (float)((pk[0] >>  8) & 0xffu);
        s0[2] = (float)((pk[0] >> 16) & 0xffu);
    }

    // ---- final output OUT_LEN-1 (window m=16 of last thread: w[16..31]) ----
    if (isLast) {
        const float wm = w[15], wn = w[31];
        int s = 0;
        #pragma unroll
        for (int j = 16; j < 31; ++j) {
            R[j] += (int)(w[j] < wm);
            int c2 = (wn < w[j]);
            R[j] += c2;
            s    += c2;
        }
        R[31] = 31 - s;                       // (15-s) + 16 bias
        int sel = 0; float val = w[16];
        #pragma unroll
        for (int j = 16; j < 32; ++j) {
            bool c = (R[j] == 23);            // 7 + 16
            sel = c ? (j - 16) : sel;
            val = c ? w[j]     : val;
        }
        dout[OUT_LEN - 1]     = val;
        dout[2 * OUT_LEN - 1] = (float)sel;
    }
}

extern "C" void kernel_launch(void* const* d_in, const int* in_sizes, int n_in,
                              void* d_out, int out_size, void* d_ws, size_t ws_size,
                              hipStream_t stream) {
    const float* x = (const float*)d_in[0];
    float* out = (float*)d_out;
    rankpool_kernel<<<NBLK, TPB, 0, stream>>>(x, out);
}